// Round 1
// baseline (1027.153 us; speedup 1.0000x reference)
//
#include <hip/hip_runtime.h>

typedef unsigned short u16;
typedef unsigned int u32;
typedef __attribute__((ext_vector_type(8))) short bfrag;   // 8 bf16
typedef __attribute__((ext_vector_type(4))) float facc;    // 4 f32

__device__ __forceinline__ u16 f2bf(float f) {
  u32 u = __builtin_bit_cast(u32, f);
  u = (u + 0x7fffu + ((u >> 16) & 1u)) >> 16;
  return (u16)u;
}
__device__ __forceinline__ float bf2f(u16 b) {
  u32 u = ((u32)b) << 16;
  return __builtin_bit_cast(float, u);
}

// bicubic 3->5 matrix (PyTorch bicubic a=-0.75, align_corners=False), precomputed
__device__ __constant__ float Mb[5][3] = {
  { 1.096f, -0.096f,  0.0f  },
  { 0.612f,  0.46f,  -0.072f},
  { 0.0f,    1.0f,    0.0f  },
  {-0.072f,  0.46f,   0.612f},
  { 0.0f,   -0.096f,  1.096f},
};

// ---------------- Kernel A: pooling pyramid -> att (b, 768, 5, 5) ----------------
__global__ __launch_bounds__(256) void att_kernel(const float* __restrict__ x,
                                                  float* __restrict__ att) {
  int bc = blockIdx.x;            // b*256 + c
  int b = bc >> 8, c = bc & 255;
  const float* xc = x + (size_t)bc * 3600;
  __shared__ float s15[225];
  __shared__ float p3s[9];
  int t = threadIdx.x;
  if (t < 225) {
    int i = t / 15, j = t - (t / 15) * 15;
    const float* base = xc + i * 4 * 60 + j * 4;
    float s = 0.f;
#pragma unroll
    for (int r = 0; r < 4; ++r) {
      float4 v = *reinterpret_cast<const float4*>(base + r * 60);
      s += v.x + v.y + v.z + v.w;
    }
    s15[t] = s;
  }
  __syncthreads();
  float a5v = 0.f;
  if (t < 25) {  // 5x5 pool (12x12 blocks = 3x3 of s15 cells)
    int ii = t / 5, jj = t - (t / 5) * 5;
    float s = 0.f;
#pragma unroll
    for (int r = 0; r < 3; ++r)
#pragma unroll
      for (int cc = 0; cc < 3; ++cc) s += s15[(ii * 3 + r) * 15 + jj * 3 + cc];
    a5v = s * (1.f / 144.f);
  }
  if (t >= 64 && t < 73) {  // 3x3 pool (20x20 blocks = 5x5 of s15 cells)
    int i3 = t - 64;
    int pi = i3 / 3, pj = i3 - pi * 3;
    float s = 0.f;
#pragma unroll
    for (int r = 0; r < 5; ++r)
#pragma unroll
      for (int cc = 0; cc < 5; ++cc) s += s15[(pi * 5 + r) * 15 + pj * 5 + cc];
    p3s[i3] = s * (1.f / 400.f);
  }
  __syncthreads();
  float* attb = att + (size_t)b * 768 * 25;
  if (t < 25) {
    attb[(512 + c) * 25 + t] = a5v;                 // a5
    int o = t / 5, q = t - (t / 5) * 5;             // a3 = M p3 M^T
    float s = 0.f;
#pragma unroll
    for (int i = 0; i < 3; ++i) {
      float mi = Mb[o][i];
#pragma unroll
      for (int j = 0; j < 3; ++j) s += mi * Mb[q][j] * p3s[i * 3 + j];
    }
    attb[(256 + c) * 25 + t] = s;
  } else if (t == 32) {
    float s = 0.f;
#pragma unroll
    for (int i = 0; i < 9; ++i) s += p3s[i];
    s *= (1.f / 9.f);                               // a1 = global mean
    for (int p = 0; p < 25; ++p) attb[c * 25 + p] = s;
  }
}

// ---------------- Kernel B: routing head -> r (b, 3, 256) ----------------
__global__ __launch_bounds__(256) void route_kernel(
    const float* __restrict__ att, const float* __restrict__ rw1,
    const float* __restrict__ rdw1, const float* __restrict__ rdw2,
    const float* __restrict__ rw2, float* __restrict__ rout) {
  int b = blockIdx.x;
  int t = threadIdx.x;
  __shared__ u16 attS[768 * 25];
  __shared__ float h1[16 * 25];
  __shared__ float h2[16 * 9];
  __shared__ float h3[16];
  const float* attb = att + (size_t)b * 768 * 25;
  for (int i = t; i < 768 * 25; i += 256) attS[i] = f2bf(attb[i]);
  __syncthreads();
  for (int idx = t; idx < 400; idx += 256) {   // 1x1 conv 768->16, relu
    int sq = idx / 25, p = idx - (idx / 25) * 25;
    const float* wrow = rw1 + sq * 768;
    float s = 0.f;
    for (int ic = 0; ic < 768; ++ic) s += wrow[ic] * bf2f(attS[ic * 25 + p]);
    h1[idx] = fmaxf(s, 0.f);
  }
  __syncthreads();
  for (int idx = t; idx < 144; idx += 256) {   // dw 3x3 valid, relu
    int sq = idx / 9, ij = idx - (idx / 9) * 9;
    int i = ij / 3, j = ij - (ij / 3) * 3;
    float s = 0.f;
#pragma unroll
    for (int u = 0; u < 3; ++u)
#pragma unroll
      for (int v = 0; v < 3; ++v)
        s += rdw1[sq * 9 + u * 3 + v] * h1[sq * 25 + (i + u) * 5 + (j + v)];
    h2[idx] = fmaxf(s, 0.f);
  }
  __syncthreads();
  if (t < 16) {                                // dw 3x3 valid -> 1x1, relu
    float s = 0.f;
#pragma unroll
    for (int uv = 0; uv < 9; ++uv) s += rdw2[t * 9 + uv] * h2[t * 9 + uv];
    h3[t] = fmaxf(s, 0.f);
  }
  __syncthreads();
  for (int idx = t; idx < 768; idx += 256) {   // 1x1 conv 16->768, sigmoid
    float s = 0.f;
#pragma unroll
    for (int sq = 0; sq < 16; ++sq) s += rw2[idx * 16 + sq] * h3[sq];
    rout[(size_t)b * 768 + idx] = 1.f / (1.f + expf(-s));
  }
}

// ---------------- Kernel C: combine expert weights -> cw bf16 (b,256,2304) ----------------
__global__ __launch_bounds__(256) void cw_kernel(const float* __restrict__ rout,
                                                 const float* __restrict__ we,
                                                 u16* __restrict__ cw) {
  int idx = blockIdx.x * 256 + threadIdx.x;  // (b,o,c)
  if (idx >= 32 * 256 * 256) return;
  int b = idx >> 16;
  int oc = idx & 65535;
  int o = oc >> 8, c = oc & 255;
  float r0 = rout[b * 768 + c];
  float r1 = rout[b * 768 + 256 + c];
  float r2 = rout[b * 768 + 512 + c];
  const size_t ES = (size_t)256 * 256 * 9;
  const float* w0 = we + ((size_t)o * 256 + c) * 9;
  u16* dst = cw + ((size_t)(b * 256 + o)) * 2304 + c * 9;
#pragma unroll
  for (int tp = 0; tp < 9; ++tp) {
    float f = r0 * w0[tp] + r1 * w0[ES + tp] + r2 * w0[2 * ES + tp];
    dst[tp] = f2bf(f);
  }
}

// ---------------- Kernel D: per-sample implicit-GEMM conv (MFMA bf16) ----------------
// M=256 (O) tiled 64, N=3600 (HW) tiled 64, K=2304 (C*9) tiled 64.
__global__ __launch_bounds__(256, 4) void conv_kernel(const float* __restrict__ x,
                                                      const u16* __restrict__ cw,
                                                      float* __restrict__ y) {
  const int b = blockIdx.z;
  const int o0 = blockIdx.y * 64;
  const int p0 = blockIdx.x * 64;
  __shared__ u16 As[64 * 72];  // [m][k], +8 pad
  __shared__ u16 Bs[64 * 72];  // [n][k], +8 pad
  const int t = threadIdx.x;
  const int wave = t >> 6, lane = t & 63;
  facc acc[4] = {};

  const u16* cwb = cw + (size_t)(b * 256 + o0) * 2304;
  const float* xb = x + (size_t)b * 256 * 3600;

  // B-gather coords for this thread: n = t/4, 16 consecutive k at (t%4)*16
  const int nb = t >> 2;
  const int kbase = (t & 3) * 16;
  const int p = p0 + nb;
  const bool pv = (p < 3600);
  const int h = p / 60, w = p - (p / 60) * 60;

  for (int kt = 0; kt < 36; ++kt) {
    const int k0 = kt * 64;
    // stage A (linear copy of cw rows)
#pragma unroll
    for (int rr = 0; rr < 2; ++rr) {
      int ch = t + rr * 256;
      int row = ch >> 3, col8 = ch & 7;
      uint4 v = *reinterpret_cast<const uint4*>(cwb + (size_t)row * 2304 + k0 + col8 * 8);
      *reinterpret_cast<uint4*>(&As[row * 72 + col8 * 8]) = v;
    }
    // stage B (im2col gather, fp32 -> bf16)
#pragma unroll 4
    for (int i = 0; i < 16; ++i) {
      int k = k0 + kbase + i;
      int c = k / 9;
      int tap = k - c * 9;
      int kh = tap / 3;
      int kw = tap - kh * 3;
      float v = 0.f;
      if (pv) {
        int ih = h + kh - 1, iw = w + kw - 1;
        if ((unsigned)ih < 60u && (unsigned)iw < 60u)
          v = xb[c * 3600 + ih * 60 + iw];
      }
      Bs[nb * 72 + kbase + i] = f2bf(v);
    }
    __syncthreads();
    // compute: wave handles rows [wave*16, wave*16+16), all 4 n-tiles
    {
      const int mrow = wave * 16 + (lane & 15);
      const int kq = (lane >> 4) * 8;
#pragma unroll
      for (int ks = 0; ks < 2; ++ks) {
        bfrag a = *reinterpret_cast<const bfrag*>(&As[mrow * 72 + ks * 32 + kq]);
#pragma unroll
        for (int nt = 0; nt < 4; ++nt) {
          bfrag bb = *reinterpret_cast<const bfrag*>(&Bs[(nt * 16 + (lane & 15)) * 72 + ks * 32 + kq]);
          acc[nt] = __builtin_amdgcn_mfma_f32_16x16x32_bf16(a, bb, acc[nt], 0, 0, 0);
        }
      }
    }
    __syncthreads();
  }
  // epilogue: D row = (lane>>4)*4 + r, col = lane&15
  const int mlo = (lane >> 4) * 4;
  const int ncol = lane & 15;
#pragma unroll
  for (int nt = 0; nt < 4; ++nt) {
    int pp = p0 + nt * 16 + ncol;
    if (pp < 3600) {
#pragma unroll
      for (int r = 0; r < 4; ++r) {
        int o = o0 + wave * 16 + mlo + r;
        y[(size_t)(b * 256 + o) * 3600 + pp] = acc[nt][r];
      }
    }
  }
}

extern "C" void kernel_launch(void* const* d_in, const int* in_sizes, int n_in,
                              void* d_out, int out_size, void* d_ws, size_t ws_size,
                              hipStream_t stream) {
  const float* x    = (const float*)d_in[0];
  const float* we   = (const float*)d_in[1];
  const float* rw1  = (const float*)d_in[2];
  const float* rdw1 = (const float*)d_in[3];
  const float* rdw2 = (const float*)d_in[4];
  const float* rw2  = (const float*)d_in[5];
  float* y = (float*)d_out;

  char* ws = (char*)d_ws;
  float* att  = (float*)ws;               // 614400 floats  = 2,457,600 B
  float* rout = (float*)(ws + 2457600);   // 24576 floats   =    98,304 B
  u16*   cw   = (u16*)(ws + 2555904);     // 18,874,368 u16 = 37,748,736 B

  att_kernel<<<dim3(8192), 256, 0, stream>>>(x, att);
  route_kernel<<<dim3(32), 256, 0, stream>>>(att, rw1, rdw1, rdw2, rw2, rout);
  cw_kernel<<<dim3(8192), 256, 0, stream>>>(rout, we, cw);
  conv_kernel<<<dim3(57, 4, 32), 256, 0, stream>>>(x, cw, y);
  (void)in_sizes; (void)n_in; (void)out_size; (void)ws_size;
}

// Round 2
// 244.714 us; speedup vs baseline: 4.1974x; 4.1974x over previous
//
#include <hip/hip_runtime.h>

typedef unsigned short u16;
typedef unsigned int u32;
typedef __attribute__((ext_vector_type(8))) short bfrag;   // 8 bf16
typedef __attribute__((ext_vector_type(4))) float facc;    // 4 f32

#define GAS __attribute__((address_space(1)))
#define LAS __attribute__((address_space(3)))

__device__ __forceinline__ u16 f2bf(float f) {
  u32 u = __builtin_bit_cast(u32, f);
  u = (u + 0x7fffu + ((u >> 16) & 1u)) >> 16;
  return (u16)u;
}
__device__ __forceinline__ float bf2f(u16 b) {
  u32 u = ((u32)b) << 16;
  return __builtin_bit_cast(float, u);
}

__device__ __forceinline__ void glds16(const u16* src, u16* dst) {
  __builtin_amdgcn_global_load_lds((const GAS unsigned int*)src,
                                   (LAS unsigned int*)dst, 16, 0, 0);
}

// bicubic 3->5 matrix (PyTorch bicubic a=-0.75, align_corners=False), precomputed
__device__ __constant__ float Mb[5][3] = {
  { 1.096f, -0.096f,  0.0f  },
  { 0.612f,  0.46f,  -0.072f},
  { 0.0f,    1.0f,    0.0f  },
  {-0.072f,  0.46f,   0.612f},
  { 0.0f,   -0.096f,  1.096f},
};

// ---------------- Kernel A: pooling pyramid -> att (b, 768, 5, 5) ----------------
__global__ __launch_bounds__(256) void att_kernel(const float* __restrict__ x,
                                                  float* __restrict__ att) {
  int bc = blockIdx.x;            // b*256 + c
  int b = bc >> 8, c = bc & 255;
  const float* xc = x + (size_t)bc * 3600;
  __shared__ float s15[225];
  __shared__ float p3s[9];
  int t = threadIdx.x;
  if (t < 225) {
    int i = t / 15, j = t - (t / 15) * 15;
    const float* base = xc + i * 4 * 60 + j * 4;
    float s = 0.f;
#pragma unroll
    for (int r = 0; r < 4; ++r) {
      float4 v = *reinterpret_cast<const float4*>(base + r * 60);
      s += v.x + v.y + v.z + v.w;
    }
    s15[t] = s;
  }
  __syncthreads();
  float a5v = 0.f;
  if (t < 25) {
    int ii = t / 5, jj = t - (t / 5) * 5;
    float s = 0.f;
#pragma unroll
    for (int r = 0; r < 3; ++r)
#pragma unroll
      for (int cc = 0; cc < 3; ++cc) s += s15[(ii * 3 + r) * 15 + jj * 3 + cc];
    a5v = s * (1.f / 144.f);
  }
  if (t >= 64 && t < 73) {
    int i3 = t - 64;
    int pi = i3 / 3, pj = i3 - pi * 3;
    float s = 0.f;
#pragma unroll
    for (int r = 0; r < 5; ++r)
#pragma unroll
      for (int cc = 0; cc < 5; ++cc) s += s15[(pi * 5 + r) * 15 + pj * 5 + cc];
    p3s[i3] = s * (1.f / 400.f);
  }
  __syncthreads();
  float* attb = att + (size_t)b * 768 * 25;
  if (t < 25) {
    attb[(512 + c) * 25 + t] = a5v;                 // a5
    int o = t / 5, qq = t - (t / 5) * 5;            // a3 = M p3 M^T
    float s = 0.f;
#pragma unroll
    for (int i = 0; i < 3; ++i) {
      float mi = Mb[o][i];
#pragma unroll
      for (int j = 0; j < 3; ++j) s += mi * Mb[qq][j] * p3s[i * 3 + j];
    }
    attb[(256 + c) * 25 + t] = s;
  } else if (t == 32) {
    float s = 0.f;
#pragma unroll
    for (int i = 0; i < 9; ++i) s += p3s[i];
    s *= (1.f / 9.f);                               // a1 = global mean
    for (int p = 0; p < 25; ++p) attb[c * 25 + p] = s;
  }
}

// ---------------- Kernel B: routing head -> r (b, 3, 256) ----------------
__global__ __launch_bounds__(256) void route_kernel(
    const float* __restrict__ att, const float* __restrict__ rw1,
    const float* __restrict__ rdw1, const float* __restrict__ rdw2,
    const float* __restrict__ rw2, float* __restrict__ rout) {
  int b = blockIdx.x;
  int t = threadIdx.x;
  __shared__ u16 attS[768 * 25];
  __shared__ float h1[16 * 25];
  __shared__ float h2[16 * 9];
  __shared__ float h3[16];
  const float* attb = att + (size_t)b * 768 * 25;
  for (int i = t; i < 768 * 25; i += 256) attS[i] = f2bf(attb[i]);
  __syncthreads();
  for (int idx = t; idx < 400; idx += 256) {
    int sq = idx / 25, p = idx - (idx / 25) * 25;
    const float* wrow = rw1 + sq * 768;
    float s = 0.f;
    for (int ic = 0; ic < 768; ++ic) s += wrow[ic] * bf2f(attS[ic * 25 + p]);
    h1[idx] = fmaxf(s, 0.f);
  }
  __syncthreads();
  for (int idx = t; idx < 144; idx += 256) {
    int sq = idx / 9, ij = idx - (idx / 9) * 9;
    int i = ij / 3, j = ij - (ij / 3) * 3;
    float s = 0.f;
#pragma unroll
    for (int u = 0; u < 3; ++u)
#pragma unroll
      for (int v = 0; v < 3; ++v)
        s += rdw1[sq * 9 + u * 3 + v] * h1[sq * 25 + (i + u) * 5 + (j + v)];
    h2[idx] = fmaxf(s, 0.f);
  }
  __syncthreads();
  if (t < 16) {
    float s = 0.f;
#pragma unroll
    for (int uv = 0; uv < 9; ++uv) s += rdw2[t * 9 + uv] * h2[t * 9 + uv];
    h3[t] = fmaxf(s, 0.f);
  }
  __syncthreads();
  for (int idx = t; idx < 768; idx += 256) {
    float s = 0.f;
#pragma unroll
    for (int sq = 0; sq < 16; ++sq) s += rw2[idx * 16 + sq] * h3[sq];
    rout[(size_t)b * 768 + idx] = 1.f / (1.f + expf(-s));
  }
}

// ---------------- Kernel C: combine expert weights -> cw bf16 (b,256, k=(ct*9+tap)*64+cl) ----------------
__global__ __launch_bounds__(256) void cw_kernel(const float* __restrict__ rout,
                                                 const float* __restrict__ we,
                                                 u16* __restrict__ cw) {
  int idx = blockIdx.x * 256 + threadIdx.x;  // (b,o,c)
  if (idx >= 32 * 256 * 256) return;
  int b = idx >> 16;
  int oc = idx & 65535;
  int o = oc >> 8, c = oc & 255;
  float r0 = rout[b * 768 + c];
  float r1 = rout[b * 768 + 256 + c];
  float r2 = rout[b * 768 + 512 + c];
  const size_t ES = (size_t)256 * 256 * 9;
  const float* w0 = we + ((size_t)o * 256 + c) * 9;
  int ctile = c >> 6, c_loc = c & 63;
  u16* dst = cw + ((size_t)(b * 256 + o)) * 2304 + ctile * 576 + c_loc;
#pragma unroll
  for (int tp = 0; tp < 9; ++tp) {
    float f = r0 * w0[tp] + r1 * w0[ES + tp] + r2 * w0[2 * ES + tp];
    dst[tp * 64] = f2bf(f);
  }
}

// ---------------- Kernel P: x (NCHW f32) -> xpad[b][62][64][256] bf16 zero-padded ----------------
__global__ __launch_bounds__(256) void xprep_kernel(const float* __restrict__ x,
                                                    u16* __restrict__ xpad) {
  const int row = blockIdx.x;        // 0..61 (input row = row-1)
  const int b = blockIdx.y;
  const int t = threadIdx.x;
  u16* outrow = xpad + ((size_t)(b * 62 + row)) * 64 * 256;   // [64 col][256 c]
  if (row == 0 || row == 61) {
    uint4 z = {0, 0, 0, 0};
#pragma unroll
    for (int i = 0; i < 8; ++i)
      *reinterpret_cast<uint4*>(outrow + (size_t)(t + i * 256) * 8) = z;
    return;
  }
  const int h = row - 1;
  __shared__ float xs[64 * 62];      // [c_loc][62] (pad to break bank stride)
  const float* xb = x + ((size_t)b * 256) * 3600 + h * 60;
  for (int cc = 0; cc < 4; ++cc) {
    for (int u = t; u < 960; u += 256) {
      int c = u / 15, seg = u - (u / 15) * 15;
      float4 v = *reinterpret_cast<const float4*>(xb + (size_t)(cc * 64 + c) * 3600 + seg * 4);
      float* d = &xs[c * 62 + seg * 4];
      d[0] = v.x; d[1] = v.y; d[2] = v.z; d[3] = v.w;
    }
    __syncthreads();
    for (int u = t; u < 512; u += 256) {
      int col = u >> 3, slot = u & 7;
      uint4 o = {0, 0, 0, 0};
      if (col >= 1 && col <= 60) {
        int w = col - 1;
        u16 tmp[8];
#pragma unroll
        for (int j = 0; j < 8; ++j) tmp[j] = f2bf(xs[(slot * 8 + j) * 62 + w]);
        o = *reinterpret_cast<uint4*>(tmp);
      }
      *reinterpret_cast<uint4*>(outrow + (size_t)col * 256 + cc * 64 + slot * 8) = o;
    }
    __syncthreads();
  }
}

// ---------------- Kernel D: per-sample implicit-GEMM conv (MFMA bf16, tap-decomposed) ----------------
// Block: 128 O x 128 px (2 rows x 64 cols). 4 waves (2m x 2n), wave-tile 64x64.
// LDS: xtile [4 rows][64 cols][64 c] 32KB @0; A dbuf 2 x [128 m][64 c] 16KB @16384/@24576.
__global__ __launch_bounds__(256, 2) void conv_kernel(const u16* __restrict__ xpad,
                                                      const u16* __restrict__ cw,
                                                      float* __restrict__ y) {
  __shared__ __align__(16) u16 smem[32768];   // 64 KB exactly

  const int flat = blockIdx.x;
  const int wg = (flat & 7) * 240 + (flat >> 3);     // bijective XCD swizzle (1920 % 8 == 0)
  const int b = wg / 60;
  const int r2 = wg - b * 60;
  const int ot = r2 / 30, rp = r2 - (r2 / 30) * 30;
  const int o0 = ot * 128, h0 = rp * 2;

  const int t = threadIdx.x;
  const int wave = t >> 6, lane = t & 63;
  const int wm = wave >> 1, wn = wave & 1;
  const int q = lane >> 4, r16 = lane & 15, l7 = lane & 7;

  const u16* cwB = cw + (size_t)(b * 256 + o0) * 2304;
  const u16* xpB = xpad + ((size_t)(b * 62 + h0) * 64) * 256;

  // ---- per-lane staging terms (linear LDS dest, pre-swizzled global source) ----
  int a_src[4], a_du[4];
#pragma unroll
  for (int i = 0; i < 4; ++i) {
    int u = wave * 256 + i * 64 + lane;          // 1024 units of 16B = 16KB
    int m = u >> 3, sd = u & 7, ss = sd ^ (m & 7);
    a_src[i] = m * 2304 + ss * 8;
    a_du[i] = u * 8;
  }
  int x_src[8], x_du[8];
#pragma unroll
  for (int i = 0; i < 8; ++i) {
    int u = wave * 512 + i * 64 + lane;          // 2048 units of 16B = 32KB
    int row = u >> 9, col = (u >> 3) & 63, sd = u & 7, ss = sd ^ (col & 7);
    x_src[i] = (row * 64 + col) * 256 + ss * 8;
    x_du[i] = u * 8;
  }

  // ---- per-lane read terms ----
  const int abase = (wm * 64 + r16) * 64;        // + mf*1024 + aq, ^ks*32
  const int aq = (q ^ l7) * 8;
  int bct[3];
#pragma unroll
  for (int kw = 0; kw < 3; ++kw) {
    int rk = r16 + kw;
    bct[kw] = rk * 64 + ((q ^ (rk & 7)) * 8);
  }

  facc acc[4][4] = {};

  auto stageA = [&](int koff, int bufsel) {
    u16* dst = smem + 16384 + bufsel * 8192;
#pragma unroll
    for (int i = 0; i < 4; ++i) glds16(cwB + a_src[i] + koff, dst + a_du[i]);
  };
  auto stageX = [&](int ct) {
#pragma unroll
    for (int i = 0; i < 8; ++i) glds16(xpB + x_src[i] + ct * 64, smem + x_du[i]);
  };

  stageX(0);
  stageA(0, 0);
  __syncthreads();

  for (int ct = 0; ct < 4; ++ct) {
#pragma unroll
    for (int tap = 0; tap < 9; ++tap) {
      const int cur = (ct + tap) & 1;
      const bool last = (ct == 3 && tap == 8);
      if (!last) stageA((ct * 9 + tap + 1) * 64, cur ^ 1);
      // compute this tap
      {
        const int kh = tap / 3, kw = tap % 3;
        const u16* Ab = smem + 16384 + cur * 8192;
        const int bbase = (wn + kh) * 4096 + bct[kw];
#pragma unroll
        for (int ks = 0; ks < 2; ++ks) {
          const int kx = ks * 32;
          bfrag a[4], bb[4];
#pragma unroll
          for (int mf = 0; mf < 4; ++mf)
            a[mf] = *reinterpret_cast<const bfrag*>(Ab + ((abase + mf * 1024 + aq) ^ kx));
#pragma unroll
          for (int nf = 0; nf < 4; ++nf)
            bb[nf] = *reinterpret_cast<const bfrag*>(smem + ((bbase + nf * 1024) ^ kx));
#pragma unroll
          for (int mf = 0; mf < 4; ++mf)
#pragma unroll
            for (int nf = 0; nf < 4; ++nf)
              acc[mf][nf] = __builtin_amdgcn_mfma_f32_16x16x32_bf16(a[mf], bb[nf], acc[mf][nf], 0, 0, 0);
        }
      }
      __syncthreads();
      if (tap == 8 && ct < 3) { stageX(ct + 1); __syncthreads(); }
    }
  }

  // ---- epilogue ----
  float* yB = y + (size_t)(b * 256 + o0 + wm * 64) * 3600 + (size_t)(h0 + wn) * 60;
#pragma unroll
  for (int mf = 0; mf < 4; ++mf)
#pragma unroll
    for (int nf = 0; nf < 4; ++nf) {
      int w = nf * 16 + r16;
      if (w < 60) {
#pragma unroll
        for (int rr = 0; rr < 4; ++rr) {
          int o_loc = mf * 16 + q * 4 + rr;
          yB[(size_t)o_loc * 3600 + w] = acc[mf][nf][rr];
        }
      }
    }
}

extern "C" void kernel_launch(void* const* d_in, const int* in_sizes, int n_in,
                              void* d_out, int out_size, void* d_ws, size_t ws_size,
                              hipStream_t stream) {
  const float* x    = (const float*)d_in[0];
  const float* we   = (const float*)d_in[1];
  const float* rw1  = (const float*)d_in[2];
  const float* rdw1 = (const float*)d_in[3];
  const float* rdw2 = (const float*)d_in[4];
  const float* rw2  = (const float*)d_in[5];
  float* y = (float*)d_out;

  char* ws = (char*)d_ws;
  float* att  = (float*)ws;                    // 2,457,600 B
  float* rout = (float*)(ws + 2457600);        //    98,304 B
  u16*   cwp  = (u16*)(ws + 2555904);          // 37,748,736 B
  u16*   xpad = (u16*)(ws + 40304640);         // 65,011,712 B  (total 105,316,352)

  xprep_kernel<<<dim3(62, 32), 256, 0, stream>>>(x, xpad);
  att_kernel<<<8192, 256, 0, stream>>>(x, att);
  route_kernel<<<32, 256, 0, stream>>>(att, rw1, rdw1, rdw2, rw2, rout);
  cw_kernel<<<8192, 256, 0, stream>>>(rout, we, cwp);
  conv_kernel<<<1920, 256, 0, stream>>>(xpad, cwp, y);
  (void)in_sizes; (void)n_in; (void)out_size; (void)ws_size;
}